// Round 5
// baseline (179.535 us; speedup 1.0000x reference)
//
#include <hip/hip_runtime.h>
#include <math.h>

// Problem constants (B, C, H, W) = (32, 10, 192, 320), fp32.
constexpr int B_ = 32, C_ = 10, H_ = 192, W_ = 320;
constexpr int HW_  = H_ * W_;        // 61440
constexpr int CHW_ = C_ * HW_;       // 614400
constexpr int NPTS = B_ * HW_;       // 1966080 spatial points

// Software-pipelined persistent tiling:
//   TPB=128 threads (2 waves), PPT=2 points/thread/tile (float2 loads),
//   TILES=6 consecutive tiles per block (256 points each, 1536-pt span),
//   NBLK=1280 blocks = exactly 5 per CU. 1280*1536 = 1,966,080 = NPTS.
// Span 1536 divides HW_ (61440/1536 = 40) -> a block never crosses b.
constexpr int TPB   = 128;
constexpr int PPT   = 2;
constexpr int TILES = 6;
constexpr int TPTS  = TPB * PPT;             // 256 points per tile
constexpr int BSPAN = TPTS * TILES;          // 1536 points per block
constexpr int NBLK  = NPTS / BSPAN;          // 1280 blocks

// Partial-sum slots, ws[slot * NBLK + blk]. Final weights folded per-thread:
// 0: nv  1: num_pos
// 2: sum pos*(g0-r0)^2*log(safe+EPS)            (pos_term = -this)
// 3: sum neg*r0^2*log(1+EPS-safe)*(1-g0)^4      (neg_term = -this)
// 4: P  = 0.5*s_pos + 0.5*s_const + 0.1*s_h     (-> P/nv)
// 5: V1 = 0.05*s_len1 + 0.5*s_trig1             (-> V1/nv)
// 6: V2 = 0.05*s_len2 + 0.5*s_trig2             (-> V2/nv)
// loss = focal + (P + min(V1,V2)) / nv
#define NACC 7

__device__ __forceinline__ float sl1f(float d) {
    float ad = fabsf(d);
    return ad < 1.0f ? 0.5f * d * d : ad - 0.5f;
}

// Round-8 rationale: three failed attempts to hold a straight-line register
// epoch (R1/R2/R4: compiler sinks loads per-use at IR level; VGPR counter
// proved the epoch never existed). R3 (LDS-staged, structure VERIFIED) had
// 120KB/CU in flight yet same 4.3 B/cyc -> queueing-saturated, but with a
// duty-cycle confound (3 lockstep blocks/CU, drain-to-zero each tile).
// This kernel removes the confound the one way the compiler cannot defeat:
// LOOP-CARRIED prefetch. Loads issued in iteration k are consumed in k+1 --
// they cannot sink across the back-edge. Steady state: ~20 loads in flight
// per wave across the entire sweep, no drain-to-zero, no block-exit gaps.
// Compiler auto-emits counted vmcnt waits (first use of A waits vmcnt(20),
// leaving B's 20 loads in flight) -- the m97 counted-vmcnt pattern.
__global__ __launch_bounds__(TPB) void loss_main(
    const float* __restrict__ re, const float* __restrict__ gt,
    float* __restrict__ ws)
{
    const int p0 = blockIdx.x * BSPAN + threadIdx.x * PPT;  // tile-0 point
    const int b  = p0 / HW_;                                // same b for all 6 tiles
    const int s0 = p0 - b * HW_;
    const float* rp = re + (size_t)b * CHW_ + s0;
    const float* gp = gt + (size_t)b * CHW_ + s0;

    float acc[NACC];
#pragma unroll
    for (int i = 0; i < NACC; ++i) acc[i] = 0.0f;

    float2 RA[10], GA[10], RB[10], GB[10];

    // Issue: 20 independent coalesced dwordx2 loads for one tile.
#define ISSUE(Rb_, Gb_, OFF) do {                                         \
        _Pragma("unroll")                                                 \
        for (int c = 0; c < 10; ++c) {                                    \
            Rb_[c] = *(const float2*)(rp + c * HW_ + (OFF));              \
            Gb_[c] = *(const float2*)(gp + c * HW_ + (OFF));              \
        }                                                                 \
    } while (0)

    // Compute: full loss body for one tile's PPT points.
#define COMPUTE(Rb_, Gb_) do {                                            \
        _Pragma("unroll")                                                 \
        for (int j = 0; j < PPT; ++j) {                                   \
            const float g = ((const float*)&Gb_[0])[j];                   \
            const float r = ((const float*)&Rb_[0])[j];                   \
            const float m = (g == 1.0f) ? 1.0f : 0.0f;                    \
            acc[0] += m;                                                  \
            const float pos = (g >= 0.1f) ? 1.0f : 0.0f;                  \
            const float neg = ((g >= 0.0f) && (g < 0.1f)) ? 1.0f : 0.0f;  \
            acc[1] += pos;                                                \
            const float safe = fminf(fmaxf(r, 1e-6f), 1.0f - 1e-6f);      \
            const float larg = (pos != 0.0f) ? (safe + 6e-8f)             \
                                             : (1.0f + 6e-8f - safe);     \
            const float lg = logf(larg);                                  \
            const float d0 = g - r;                                       \
            acc[2] += pos * (d0 * d0) * lg;                               \
            const float omg = 1.0f - g;                                   \
            const float omg2 = omg * omg;                                 \
            acc[3] += neg * (r * r) * (omg2 * omg2) * lg;                 \
            const float r1 = ((const float*)&Rb_[1])[j];                  \
            const float r2 = ((const float*)&Rb_[2])[j];                  \
            const float r3 = ((const float*)&Rb_[3])[j];                  \
            const float r4v = ((const float*)&Rb_[4])[j];                 \
            const float r5 = ((const float*)&Rb_[5])[j];                  \
            const float r6 = ((const float*)&Rb_[6])[j];                  \
            const float r7 = ((const float*)&Rb_[7])[j];                  \
            const float r8 = ((const float*)&Rb_[8])[j];                  \
            const float r9 = ((const float*)&Rb_[9])[j];                  \
            const float g1 = ((const float*)&Gb_[1])[j];                  \
            const float g2 = ((const float*)&Gb_[2])[j];                  \
            const float g3 = ((const float*)&Gb_[3])[j];                  \
            const float g4v = ((const float*)&Gb_[4])[j];                 \
            const float g5 = ((const float*)&Gb_[5])[j];                  \
            const float g6 = ((const float*)&Gb_[6])[j];                  \
            const float g7 = ((const float*)&Gb_[7])[j];                  \
            const float g8 = ((const float*)&Gb_[8])[j];                  \
            const float g9 = ((const float*)&Gb_[9])[j];                  \
            const float sp = sl1f(r1 - g1) + sl1f(r2 - g2);               \
            const float c1 = 1.0f - r5 * r5 - r4v * r4v;                  \
            const float c2 = 1.0f - r8 * r8 - r7 * r7;                    \
            const float sc = c1 * c1 + c2 * c2;                           \
            const float sh = sl1f(r9 - g9);                               \
            acc[4] += m * (0.5f * sp + 0.5f * sc + 0.1f * sh);            \
            const float d44 = r4v - g4v, d77 = r7 - g7;                   \
            const float d55 = r5 - g5,  d88 = r8 - g8;                    \
            const float t1 = d44*d44 + d77*d77 + d55*d55 + d88*d88;       \
            const float l1 = sl1f(r3 - g3) + sl1f(r6 - g6);               \
            acc[5] += m * (0.05f * l1 + 0.5f * t1);                       \
            const float d47 = r4v - g7, d74 = r7 - g4v;                   \
            const float d58 = r5 - g8,  d85 = r8 - g5;                    \
            const float t2 = d47*d47 + d74*d74 + d58*d58 + d85*d85;       \
            const float l2 = sl1f(r3 - g6) + sl1f(r6 - g3);               \
            acc[6] += m * (0.05f * l2 + 0.5f * t2);                       \
        }                                                                 \
    } while (0)

    // Prologue: tile 0 into A.
    ISSUE(RA, GA, 0);

    // Steady state: 2 tiles per iteration, buffers statically named (no
    // runtime indexing -> no scratch). A-loads for the next iteration are
    // loop-carried: the back-edge pins them before compute, guaranteeing
    // in-flight loads during the whole iteration.
#pragma unroll 1
    for (int k = 0; k < TILES / 2; ++k) {
        const int toff = k * (2 * TPTS);
        ISSUE(RB, GB, toff + TPTS);          // tile 2k+1
        COMPUTE(RA, GA);                     // waits A only (vmcnt(20)), B in flight
        if (k + 1 < TILES / 2)
            ISSUE(RA, GA, toff + 2 * TPTS);  // tile 2k+2, consumed next iteration
        COMPUTE(RB, GB);                     // waits B; next A in flight
    }
#undef ISSUE
#undef COMPUTE

    // block reduction: wave shuffle (64 lanes) -> LDS (2 waves) -> plain store
    __shared__ float smem[NACC][2];
    const int lane = threadIdx.x & 63;
    const int wid  = threadIdx.x >> 6;
#pragma unroll
    for (int i = 0; i < NACC; ++i) {
        float v = acc[i];
#pragma unroll
        for (int off = 32; off > 0; off >>= 1) v += __shfl_down(v, off, 64);
        if (lane == 0) smem[i][wid] = v;
    }
    __syncthreads();
    if (threadIdx.x < NACC) {
        const int i = threadIdx.x;
        ws[i * NBLK + blockIdx.x] = smem[i][0] + smem[i][1];
    }
}

// One block, 640 threads: 640*2 = 1280 exact -> guard-free, all 14 loads per
// thread independent, single load epoch.
__global__ __launch_bounds__(640) void loss_reduce(
    const float* __restrict__ ws, float* __restrict__ out)
{
    float acc[NACC];
#pragma unroll
    for (int i = 0; i < NACC; ++i) acc[i] = 0.0f;

#pragma unroll
    for (int k = 0; k < 2; ++k) {
        const int idx = threadIdx.x + k * 640;
#pragma unroll
        for (int i = 0; i < NACC; ++i)
            acc[i] += ws[i * NBLK + idx];
    }

    __shared__ float smem[NACC][10];
    const int lane = threadIdx.x & 63;
    const int wid  = threadIdx.x >> 6;
#pragma unroll
    for (int i = 0; i < NACC; ++i) {
        float v = acc[i];
#pragma unroll
        for (int off = 32; off > 0; off >>= 1) v += __shfl_down(v, off, 64);
        if (lane == 0) smem[i][wid] = v;
    }
    __syncthreads();

    if (threadIdx.x == 0) {
        float slot[NACC];
#pragma unroll
        for (int i = 0; i < NACC; ++i) {
            float v = 0.0f;
#pragma unroll
            for (int w = 0; w < 10; ++w) v += smem[i][w];
            slot[i] = v;
        }
        const float nv    = slot[0];
        const float npos  = slot[1];
        const float pterm = -slot[2];
        const float nterm = -slot[3];
        const float focal = (npos == 0.0f) ? nterm : (pterm + nterm) / npos;
        out[0] = focal + (slot[4] + fminf(slot[5], slot[6])) / nv;
    }
}

extern "C" void kernel_launch(void* const* d_in, const int* in_sizes, int n_in,
                              void* d_out, int out_size, void* d_ws, size_t ws_size,
                              hipStream_t stream)
{
    const float* re = (const float*)d_in[0];
    const float* gt = (const float*)d_in[1];
    float* ws  = (float*)d_ws;
    float* out = (float*)d_out;

    loss_main<<<NBLK, TPB, 0, stream>>>(re, gt, ws);
    loss_reduce<<<1, 640, 0, stream>>>(ws, out);
}